// Round 3
// baseline (124.982 us; speedup 1.0000x reference)
//
#include <hip/hip_runtime.h>

// RGBuvHistBlock: soft histogram, 64 bins in [-1,1], sigma=0.02.
// sigma = 0.63*binwidth -> Gaussian support ~ +/-4 bins. Per pixel: find
// nearest bin k = rint(63*x), evaluate exp2(d^2*C) for j=k-4..k+4 only
// (truncation error ~1e-7 normalized vs threshold 3.4e-4), accumulate via
// per-wave LDS float atomics (runtime bin index can't hit register acc[]).

#define NCH   24        // 8*3 channels
#define HW    65536     // 256*256
#define BPC   32        // blocks per channel
#define NBIN  64
#define WIN   4         // +/- bins evaluated
#define DELTA (2.0f / 63.0f)
// C = -1/(2*sigma^2) * log2(e) = -1250 * 1.4426950408889634
#define EXP_C (-1803.3688011112042f)

__global__ __launch_bounds__(256) void hist_accum(const float* __restrict__ x,
                                                  float* __restrict__ part) {
    const int ch  = blockIdx.x >> 5;   // / BPC
    const int sub = blockIdx.x & 31;   // % BPC
    // block: 2048 pixels = 512 float4; 256 threads x 2 iters
    const float4* xv = reinterpret_cast<const float4*>(x) + ch * (HW / 4) + sub * 512;

    __shared__ float lh[4][NBIN];      // per-wave histogram (1 KB)
    const int tid  = threadIdx.x;
    const int wid  = tid >> 6;
    const int lane = tid & 63;
    lh[wid][lane] = 0.0f;              // 64 lanes zero their wave's 64 bins
    __syncthreads();

    float* myh = lh[wid];

#pragma unroll
    for (int it = 0; it < 2; ++it) {
        float4 v = xv[it * 256 + tid];
        float px[4] = {v.x, v.y, v.z, v.w};
#pragma unroll
        for (int q = 0; q < 4; ++q) {
            // p = 2x-1; nearest bin k = rint((p+1)/DELTA) = rint(63x)
            const float pp = 63.0f * px[q];
            const float kf = rintf(pp);
            const int   ki = (int)kf;
            const float d0 = (pp - kf) * DELTA;   // p - bin_val[k]
#pragma unroll
            for (int m = -WIN; m <= WIN; ++m) {
                const float d = d0 - (float)m * DELTA;  // compile-time const per m
                const float w = __builtin_amdgcn_exp2f(d * (d * EXP_C));
                const int j = ki + m;
                if ((unsigned)j < (unsigned)NBIN) atomicAdd(&myh[j], w);
            }
        }
    }
    __syncthreads();
    // combine 4 wave rows; plain store to private slot (no init, no atomics)
    if (tid < NBIN) {
        const float s = lh[0][tid] + lh[1][tid] + lh[2][tid] + lh[3][tid];
        part[(ch * BPC + sub) * NBIN + tid] = s;
    }
}

__global__ __launch_bounds__(256) void hist_norm(const float* __restrict__ part,
                                                 float* __restrict__ out) {
    const int ch  = blockIdx.x;
    const int t   = threadIdx.x;
    const int bin = t & 63;
    const int grp = t >> 6;            // 0..3
    const float* p = part + ch * (BPC * NBIN);
    float s = 0.0f;
#pragma unroll
    for (int i = 0; i < 8; ++i)        // each grp reduces 8 of the 32 sub-partials
        s += p[(grp * 8 + i) * NBIN + bin];
    __shared__ float sacc[4][NBIN];
    sacc[grp][bin] = s;
    __syncthreads();
    if (grp == 0) {                    // one wave finishes: total + normalize
        const float h = sacc[0][bin] + sacc[1][bin] + sacc[2][bin] + sacc[3][bin];
        float tot = h;
        tot += __shfl_xor(tot, 32);
        tot += __shfl_xor(tot, 16);
        tot += __shfl_xor(tot, 8);
        tot += __shfl_xor(tot, 4);
        tot += __shfl_xor(tot, 2);
        tot += __shfl_xor(tot, 1);
        out[ch * NBIN + bin] = h / (tot + 1e-8f);
    }
}

extern "C" void kernel_launch(void* const* d_in, const int* in_sizes, int n_in,
                              void* d_out, int out_size, void* d_ws, size_t ws_size,
                              hipStream_t stream) {
    const float* x = (const float*)d_in[0];
    float* part = (float*)d_ws;        // 24*32*64*4 = 192 KB, fully overwritten

    hist_accum<<<NCH * BPC, 256, 0, stream>>>(x, part);
    hist_norm<<<NCH, 256, 0, stream>>>(part, (float*)d_out);
}

// Round 4
// 63.603 us; speedup vs baseline: 1.9650x; 1.9650x over previous
//
#include <hip/hip_runtime.h>

// RGBuvHistBlock: soft histogram, 64 bins in [-1,1], sigma=0.02.
// sigma = 0.63*binwidth -> Gaussian support ~ +/-3 bins (truncation ~4e-9
// normalized vs threshold 3.4e-4). Per pixel: k = rint(63x), evaluate
// exp2(d^2*C) for the 7 bins k-3..k+3, accumulate into a PER-THREAD private
// LDS column (no atomics: R3 showed shared-float atomicAdd = CAS loop, 72us).
// 3 guard rows each side absorb out-of-range visits -> no bounds checks.

#define NCH   24        // 8*3 channels
#define HW    65536     // 256*256
#define BPC   32        // blocks per channel
#define NBIN  64
#define NROWS 72        // 3 guard + 64 bins + 3 guard + 2 pad (init rounding)
#define NCOL  128       // one column per thread; bank = t%32, 2 lanes/bank = free
#define DELTA (2.0f / 63.0f)
// C = -1/(2*sigma^2) * log2(e) = -1250 * 1.4426950408889634
#define EXP_C (-1803.3688011112042f)

__global__ __launch_bounds__(128) void hist_accum(const float* __restrict__ x,
                                                  float* __restrict__ part) {
    __shared__ float hist[NROWS][NCOL];          // 36 KB -> 3 blocks/CU resident
    const int ch  = blockIdx.x >> 5;
    const int sub = blockIdx.x & 31;
    const int tid = threadIdx.x;

    // zero-init: 72*128 = 9216 words = 2304 float4; 128 threads x 18
    float4* hz = reinterpret_cast<float4*>(&hist[0][0]);
#pragma unroll
    for (int i = 0; i < 18; ++i) hz[i * 128 + tid] = float4{0.f, 0.f, 0.f, 0.f};
    __syncthreads();

    // 2048 px per block; 128 threads x 4 float4 (16 px/thread), coalesced
    const float4* xv = reinterpret_cast<const float4*>(x) + ch * (HW / 4) + sub * 512;
    float4 v[4];
#pragma unroll
    for (int i = 0; i < 4; ++i) v[i] = xv[i * 128 + tid];

#pragma unroll
    for (int i = 0; i < 4; ++i) {
        float px[4] = {v[i].x, v[i].y, v[i].z, v[i].w};
#pragma unroll
        for (int q = 0; q < 4; ++q) {
            const float pp = 63.0f * px[q];
            const float kf = rintf(pp);
            const float d0 = (pp - kf) * DELTA;  // p - nearest bin val
            const int   ki = (int)kf;            // 0..63
            // visit rows ki..ki+6 == bins ki-3..ki+3 shifted by +3 guard rows
            float* base = &hist[0][tid] + ki * NCOL;
            float w[7];
#pragma unroll
            for (int m = 0; m < 7; ++m) {
                const float d = d0 - (float)(m - 3) * DELTA;
                w[m] = __builtin_amdgcn_exp2f(d * (d * EXP_C));
            }
            // private column: no cross-lane races; cross-pixel same-column
            // hazards ordered by the per-wave in-order LDS pipe.
#pragma unroll
            for (int m = 0; m < 7; ++m) base[m * NCOL] += w[m];
        }
    }
    __syncthreads();

    // reduce 128 columns per bin; wave w -> bins w*32..w*32+31, 2 rows/iter.
    // lane reads 16B of its row: contiguous tiling, near-conflict-free.
    const int wid  = tid >> 6;
    const int lane = tid & 63;
    const int half = lane >> 5;
    const int l32  = lane & 31;
    float* pout = part + (ch * BPC + sub) * NBIN;
#pragma unroll
    for (int g = 0; g < 16; ++g) {
        const int bin = wid * 32 + 2 * g + half;
        const float4 r4 = *reinterpret_cast<const float4*>(&hist[bin + 3][l32 * 4]);
        float s = (r4.x + r4.y) + (r4.z + r4.w);
        s += __shfl_xor(s, 1);
        s += __shfl_xor(s, 2);
        s += __shfl_xor(s, 4);
        s += __shfl_xor(s, 8);
        s += __shfl_xor(s, 16);   // stays within each 32-lane half
        if (l32 == 0) pout[bin] = s;
    }
}

__global__ __launch_bounds__(256) void hist_norm(const float* __restrict__ part,
                                                 float* __restrict__ out) {
    const int ch  = blockIdx.x;
    const int t   = threadIdx.x;
    const int bin = t & 63;
    const int grp = t >> 6;            // 0..3
    const float* p = part + ch * (BPC * NBIN);
    float s = 0.0f;
#pragma unroll
    for (int i = 0; i < 8; ++i)        // each grp reduces 8 of the 32 sub-partials
        s += p[(grp * 8 + i) * NBIN + bin];
    __shared__ float sacc[4][NBIN];
    sacc[grp][bin] = s;
    __syncthreads();
    if (grp == 0) {                    // one wave finishes: total + normalize
        const float h = sacc[0][bin] + sacc[1][bin] + sacc[2][bin] + sacc[3][bin];
        float tot = h;
        tot += __shfl_xor(tot, 32);
        tot += __shfl_xor(tot, 16);
        tot += __shfl_xor(tot, 8);
        tot += __shfl_xor(tot, 4);
        tot += __shfl_xor(tot, 2);
        tot += __shfl_xor(tot, 1);
        out[ch * NBIN + bin] = h / (tot + 1e-8f);
    }
}

extern "C" void kernel_launch(void* const* d_in, const int* in_sizes, int n_in,
                              void* d_out, int out_size, void* d_ws, size_t ws_size,
                              hipStream_t stream) {
    const float* x = (const float*)d_in[0];
    float* part = (float*)d_ws;        // 24*32*64*4 = 192 KB, fully overwritten

    hist_accum<<<NCH * BPC, 128, 0, stream>>>(x, part);
    hist_norm<<<NCH, 256, 0, stream>>>(part, (float*)d_out);
}

// Round 8
// 63.276 us; speedup vs baseline: 1.9752x; 1.0052x over previous
//
#include <hip/hip_runtime.h>

// RGBuvHistBlock: soft histogram, 64 bins in [-1,1], sigma=0.02.
// sigma = 0.63*binwidth -> Gaussian support: WIN=+/-2 bins (worst excluded
// weight e^-7.87=3.8e-4 per px vs kept mass 1.58; normalized per-bin error
// ~3e-6 for uniform input, vs 3.4e-4 threshold). Per pixel: k = rint(63x),
// evaluate exp2(d^2*C) for bins k-2..k+2, accumulate into a PER-THREAD
// private LDS column (no atomics — R3 showed shared-float atomicAdd = CAS
// loop, 72us). 2 guard rows each side absorb out-of-range -> no bounds checks.
// LDS pipe is the binding resource (per-CU serial): WIN=2 cuts main-loop DS
// ops 29% vs R4's WIN=3.

#define NCH   24        // 8*3 channels
#define HW    65536     // 256*256
#define BPC   32        // blocks per channel
#define NBIN  64
#define NROWS 68        // 2 guard + 64 bins + 2 guard
#define NCOL  128       // one column per thread; bank = t%32, 2 lanes/bank = free
#define DELTA (2.0f / 63.0f)
// C = -1/(2*sigma^2) * log2(e) = -1250 * 1.4426950408889634
#define EXP_C (-1803.3688011112042f)

__global__ __launch_bounds__(128) void hist_accum(const float* __restrict__ x,
                                                  float* __restrict__ part) {
    __shared__ float hist[NROWS][NCOL];          // 34.8 KB
    const int ch  = blockIdx.x >> 5;
    const int sub = blockIdx.x & 31;
    const int tid = threadIdx.x;

    // zero-init: 68*128 = 8704 words = 2176 float4; 128 threads x 17
    float4* hz = reinterpret_cast<float4*>(&hist[0][0]);
#pragma unroll
    for (int i = 0; i < 17; ++i) hz[i * 128 + tid] = float4{0.f, 0.f, 0.f, 0.f};
    __syncthreads();

    // 2048 px per block; 128 threads x 4 float4 (16 px/thread), coalesced
    const float4* xv = reinterpret_cast<const float4*>(x) + ch * (HW / 4) + sub * 512;
    float4 v[4];
#pragma unroll
    for (int i = 0; i < 4; ++i) v[i] = xv[i * 128 + tid];

#pragma unroll
    for (int i = 0; i < 4; ++i) {
        float px[4] = {v[i].x, v[i].y, v[i].z, v[i].w};
#pragma unroll
        for (int q = 0; q < 4; ++q) {
            const float pp = 63.0f * px[q];
            const float kf = rintf(pp);
            const float d0 = (pp - kf) * DELTA;  // p - nearest bin val
            const int   ki = (int)kf;            // 0..63
            // rows ki..ki+4 == bins ki-2..ki+2 shifted by +2 guard rows
            float* base = &hist[0][tid] + ki * NCOL;
            float w[5];
#pragma unroll
            for (int m = 0; m < 5; ++m) {
                const float d = d0 - (float)(m - 2) * DELTA;
                w[m] = __builtin_amdgcn_exp2f(d * (d * EXP_C));
            }
            // private column: no cross-lane races; same-wave LDS ops ordered.
#pragma unroll
            for (int m = 0; m < 5; ++m) base[m * NCOL] += w[m];
        }
    }
    __syncthreads();

    // reduce 128 columns per bin; wave w -> bins w*32..w*32+31, 2 bins/iter.
    const int wid  = tid >> 6;
    const int lane = tid & 63;
    const int half = lane >> 5;
    const int l32  = lane & 31;
    float* pout = part + (ch * BPC + sub) * NBIN;
#pragma unroll
    for (int g = 0; g < 16; ++g) {
        const int bin = wid * 32 + 2 * g + half;
        const float4 r4 = *reinterpret_cast<const float4*>(&hist[bin + 2][l32 * 4]);
        float s = (r4.x + r4.y) + (r4.z + r4.w);
        s += __shfl_xor(s, 1);
        s += __shfl_xor(s, 2);
        s += __shfl_xor(s, 4);
        s += __shfl_xor(s, 8);
        s += __shfl_xor(s, 16);   // stays within each 32-lane half
        if (l32 == 0) pout[bin] = s;
    }
}

__global__ __launch_bounds__(256) void hist_norm(const float* __restrict__ part,
                                                 float* __restrict__ out) {
    const int ch  = blockIdx.x;
    const int t   = threadIdx.x;
    const int bin = t & 63;
    const int grp = t >> 6;            // 0..3
    const float* p = part + ch * (BPC * NBIN);
    float s = 0.0f;
#pragma unroll
    for (int i = 0; i < 8; ++i)        // each grp reduces 8 of the 32 sub-partials
        s += p[(grp * 8 + i) * NBIN + bin];
    __shared__ float sacc[4][NBIN];
    sacc[grp][bin] = s;
    __syncthreads();
    if (grp == 0) {                    // one wave finishes: total + normalize
        const float h = sacc[0][bin] + sacc[1][bin] + sacc[2][bin] + sacc[3][bin];
        float tot = h;
        tot += __shfl_xor(tot, 32);
        tot += __shfl_xor(tot, 16);
        tot += __shfl_xor(tot, 8);
        tot += __shfl_xor(tot, 4);
        tot += __shfl_xor(tot, 2);
        tot += __shfl_xor(tot, 1);
        out[ch * NBIN + bin] = h / (tot + 1e-8f);
    }
}

extern "C" void kernel_launch(void* const* d_in, const int* in_sizes, int n_in,
                              void* d_out, int out_size, void* d_ws, size_t ws_size,
                              hipStream_t stream) {
    const float* x = (const float*)d_in[0];
    float* part = (float*)d_ws;        // 24*32*64*4 = 192 KB, fully overwritten

    hist_accum<<<NCH * BPC, 128, 0, stream>>>(x, part);
    hist_norm<<<NCH, 256, 0, stream>>>(part, (float*)d_out);
}